// Round 1
// baseline (853.124 us; speedup 1.0000x reference)
//
#include <hip/hip_runtime.h>

#define N_NODES 100000
#define N_EDGES 1600000
#define IN_FEAT 128
#define OUT_FEAT 64
#define SLOPE 0.22916666666666666f  // (1/8 + 1/3)/2 = 11/48

// ---------------------------------------------------------------------------
// GEMM1: h1[N,64] = feat[N,128] @ w1[128,64]
// block = 256 threads = 4 rows x 64 cols; w1 fully staged in LDS (32 KB),
// 4 feat rows staged in LDS (2 KB). LDS read w[k*64+c]: lanes read
// consecutive floats -> 2 lanes/bank (free); f[r*128+k] is wave-uniform
// -> broadcast (free).
// ---------------------------------------------------------------------------
__global__ __launch_bounds__(256) void gemm1_kernel(const float* __restrict__ feat,
                                                    const float* __restrict__ w1,
                                                    float* __restrict__ h1) {
    __shared__ float w[IN_FEAT * OUT_FEAT];   // 32 KB
    __shared__ float f[4 * IN_FEAT];          // 2 KB
    const int tid = threadIdx.x;

    // load w1: 8192 floats = 2048 float4; 256 threads x 8
    const float4* w4 = (const float4*)w1;
    float4* wl = (float4*)w;
#pragma unroll
    for (int i = 0; i < 8; ++i) wl[tid + i * 256] = w4[tid + i * 256];

    const int row0 = blockIdx.x * 4;  // N_NODES % 4 == 0
    // load 4 feat rows: 512 floats = 128 float4
    if (tid < 128) {
        const int rr = tid >> 5;   // 0..3
        const int kk = tid & 31;   // 0..31 float4 within row
        ((float4*)f)[tid] =
            ((const float4*)(feat + (size_t)(row0 + rr) * IN_FEAT))[kk];
    }
    __syncthreads();

    const int r = tid >> 6;   // 0..3
    const int c = tid & 63;   // 0..63
    float acc = 0.f;
#pragma unroll
    for (int k = 0; k < IN_FEAT; ++k)
        acc += f[r * IN_FEAT + k] * w[k * OUT_FEAT + c];
    h1[(size_t)(row0 + r) * OUT_FEAT + c] = acc;
}

// ---------------------------------------------------------------------------
// GEMM2: h2[N,64] = rrelu(agg1[N,64]) @ w2[64,64]
// rrelu fused into the input load.
// ---------------------------------------------------------------------------
__global__ __launch_bounds__(256) void gemm2_kernel(const float* __restrict__ agg1,
                                                    const float* __restrict__ w2,
                                                    float* __restrict__ h2) {
    __shared__ float w[OUT_FEAT * OUT_FEAT];  // 16 KB
    __shared__ float f[4 * OUT_FEAT];         // 1 KB
    const int tid = threadIdx.x;

    // load w2: 4096 floats = 1024 float4; 256 threads x 4
    const float4* w4 = (const float4*)w2;
    float4* wl = (float4*)w;
#pragma unroll
    for (int i = 0; i < 4; ++i) wl[tid + i * 256] = w4[tid + i * 256];

    const int row0 = blockIdx.x * 4;
    // load 4 agg rows (256 floats = 64 float4) with fused rrelu
    if (tid < 64) {
        const int rr = tid >> 4;  // 0..3
        const int kk = tid & 15;  // 0..15
        float4 v = ((const float4*)(agg1 + (size_t)(row0 + rr) * OUT_FEAT))[kk];
        v.x = v.x >= 0.f ? v.x : v.x * SLOPE;
        v.y = v.y >= 0.f ? v.y : v.y * SLOPE;
        v.z = v.z >= 0.f ? v.z : v.z * SLOPE;
        v.w = v.w >= 0.f ? v.w : v.w * SLOPE;
        ((float4*)f)[tid] = v;
    }
    __syncthreads();

    const int r = tid >> 6;
    const int c = tid & 63;
    float acc = 0.f;
#pragma unroll
    for (int k = 0; k < OUT_FEAT; ++k)
        acc += f[r * OUT_FEAT + k] * w[k * OUT_FEAT + c];
    h2[(size_t)(row0 + r) * OUT_FEAT + c] = acc;
}

// ---------------------------------------------------------------------------
// scatter_add: for each edge e: out[dst[e]][:] += h[src[e]][:]
// one wave (64 lanes) per edge, lane = column. src[e]/dst[e] reads are
// wave-uniform. Gather read is 256 B contiguous per wave.
// ---------------------------------------------------------------------------
__global__ __launch_bounds__(256) void scatter_add_kernel(const float* __restrict__ h,
                                                          const int* __restrict__ src,
                                                          const int* __restrict__ dst,
                                                          float* __restrict__ out) {
    const int e = blockIdx.x * 4 + (threadIdx.x >> 6);  // N_EDGES % 4 == 0
    const int c = threadIdx.x & 63;
    const int s = src[e];
    const int d = dst[e];
    const float v = h[(size_t)s * OUT_FEAT + c];
    atomicAdd(&out[(size_t)d * OUT_FEAT + c], v);
}

// ---------------------------------------------------------------------------
// final in-place rrelu on d_out
// ---------------------------------------------------------------------------
__global__ __launch_bounds__(256) void rrelu_kernel(float* __restrict__ x, int n4) {
    const int i = blockIdx.x * 256 + threadIdx.x;
    if (i < n4) {
        float4 v = ((float4*)x)[i];
        v.x = v.x >= 0.f ? v.x : v.x * SLOPE;
        v.y = v.y >= 0.f ? v.y : v.y * SLOPE;
        v.z = v.z >= 0.f ? v.z : v.z * SLOPE;
        v.w = v.w >= 0.f ? v.w : v.w * SLOPE;
        ((float4*)x)[i] = v;
    }
}

extern "C" void kernel_launch(void* const* d_in, const int* in_sizes, int n_in,
                              void* d_out, int out_size, void* d_ws, size_t ws_size,
                              hipStream_t stream) {
    const float* feat = (const float*)d_in[0];
    const int*   src  = (const int*)d_in[1];
    const int*   dst  = (const int*)d_in[2];
    const float* w1   = (const float*)d_in[3];
    const float* w2   = (const float*)d_in[4];
    float* out = (float*)d_out;

    float* h1 = (float*)d_ws;  // 25.6 MB; reused for h2 afterwards
    float* h2 = h1;

    const size_t agg_bytes = (size_t)N_NODES * OUT_FEAT * sizeof(float);

    // h1 = feat @ w1
    gemm1_kernel<<<N_NODES / 4, 256, 0, stream>>>(feat, w1, h1);

    // agg1 (in d_out) = scatter_sum(h1)
    hipMemsetAsync(d_out, 0, agg_bytes, stream);
    scatter_add_kernel<<<N_EDGES / 4, 256, 0, stream>>>(h1, src, dst, out);

    // h2 = rrelu(agg1) @ w2
    gemm2_kernel<<<N_NODES / 4, 256, 0, stream>>>(out, w2, h2);

    // out = scatter_sum(h2)
    hipMemsetAsync(d_out, 0, agg_bytes, stream);
    scatter_add_kernel<<<N_EDGES / 4, 256, 0, stream>>>(h2, src, dst, out);

    // out = rrelu(out)
    rrelu_kernel<<<(N_NODES * OUT_FEAT / 4 + 255) / 256, 256, 0, stream>>>(
        out, N_NODES * OUT_FEAT / 4);
}

// Round 2
// 419.825 us; speedup vs baseline: 2.0321x; 2.0321x over previous
//
#include <hip/hip_runtime.h>

#define N_NODES 100000
#define N_EDGES 1600000
#define IN_FEAT 128
#define OUT_FEAT 64
#define SLOPE 0.22916666666666666f  // (1/8 + 1/3)/2 = 11/48

// ---------------------------------------------------------------------------
// CSR build, step 1: histogram of dst
// ---------------------------------------------------------------------------
__global__ __launch_bounds__(256) void hist_kernel(const int* __restrict__ dst,
                                                   int* __restrict__ cnt) {
    const int e = blockIdx.x * 256 + threadIdx.x;
    atomicAdd(&cnt[dst[e]], 1);
}

// ---------------------------------------------------------------------------
// CSR build, step 2: per-node offsets. Wave-level exclusive scan of counts;
// one atomicAdd on a global counter per wave (1563 total) hands out bases.
// Segment placement order is non-deterministic but segments are disjoint,
// which is all the aggregation needs.
// ---------------------------------------------------------------------------
__global__ __launch_bounds__(256) void offsets_kernel(const int* __restrict__ cnt,
                                                      int* __restrict__ ptr,
                                                      int* __restrict__ cur,
                                                      int* __restrict__ counter) {
    const int n = blockIdx.x * 256 + threadIdx.x;
    const int lane = threadIdx.x & 63;
    const int v = (n < N_NODES) ? cnt[n] : 0;
    // inclusive wave scan
    int x = v;
#pragma unroll
    for (int off = 1; off < 64; off <<= 1) {
        int y = __shfl_up(x, off);
        if (lane >= off) x += y;
    }
    const int wave_total = __shfl(x, 63);
    int base = 0;
    if (lane == 63) base = atomicAdd(counter, wave_total);
    base = __shfl(base, 63);
    if (n < N_NODES) {
        const int p = base + x - v;  // exclusive prefix + base
        ptr[n] = p;
        cur[n] = p;
    }
}

// ---------------------------------------------------------------------------
// CSR build, step 3: fill. cur[] are per-node cursors (L2-resident, low
// contention: avg 16 edges per node).
// ---------------------------------------------------------------------------
__global__ __launch_bounds__(256) void fill_kernel(const int* __restrict__ src,
                                                   const int* __restrict__ dst,
                                                   int* __restrict__ cur,
                                                   int* __restrict__ csr) {
    const int e = blockIdx.x * 256 + threadIdx.x;
    const int d = dst[e];
    const int pos = atomicAdd(&cur[d], 1);
    csr[pos] = src[e];
}

// ---------------------------------------------------------------------------
// Aggregation + fused rrelu: one wave per dst node, lane = column.
// Gathers h[src] rows (h = 25.6 MB -> L3-resident); writes each output row
// exactly once (zero-degree nodes write 0), so no memset needed.
// ---------------------------------------------------------------------------
__global__ __launch_bounds__(256) void agg_rrelu_kernel(const float* __restrict__ h,
                                                        const int* __restrict__ csr,
                                                        const int* __restrict__ ptr,
                                                        const int* __restrict__ cnt,
                                                        float* __restrict__ out) {
    const int node = blockIdx.x * 4 + (threadIdx.x >> 6);
    if (node >= N_NODES) return;
    const int c = threadIdx.x & 63;
    const int beg = ptr[node];
    const int end = beg + cnt[node];
    float acc = 0.f;
    int i = beg;
    // 4-deep unroll for memory ILP on the gather
    for (; i + 4 <= end; i += 4) {
        const int s0 = csr[i], s1 = csr[i + 1], s2 = csr[i + 2], s3 = csr[i + 3];
        const float v0 = h[(size_t)s0 * OUT_FEAT + c];
        const float v1 = h[(size_t)s1 * OUT_FEAT + c];
        const float v2 = h[(size_t)s2 * OUT_FEAT + c];
        const float v3 = h[(size_t)s3 * OUT_FEAT + c];
        acc += v0 + v1 + v2 + v3;
    }
    for (; i < end; ++i) acc += h[(size_t)csr[i] * OUT_FEAT + c];
    acc = acc >= 0.f ? acc : acc * SLOPE;
    out[(size_t)node * OUT_FEAT + c] = acc;
}

// ---------------------------------------------------------------------------
// GEMM1: h1[N,128] @ w1[128,64]. 16 rows/block, 4 rows/thread, k unrolled
// by 4 with float4 f-broadcasts -> ~1 LDS clk per FMA.
// ---------------------------------------------------------------------------
__global__ __launch_bounds__(256) void gemm1_kernel(const float* __restrict__ feat,
                                                    const float* __restrict__ w1,
                                                    float* __restrict__ h1) {
    __shared__ float w[IN_FEAT * OUT_FEAT];  // 32 KB
    __shared__ float f[16 * IN_FEAT];        // 8 KB
    const int tid = threadIdx.x;

    const float4* w4 = (const float4*)w1;
    float4* wl = (float4*)w;
#pragma unroll
    for (int i = 0; i < 8; ++i) wl[tid + i * 256] = w4[tid + i * 256];

    const int row0 = blockIdx.x * 16;  // 100000 % 16 == 0
    const float4* fg = (const float4*)(feat + (size_t)row0 * IN_FEAT);
    float4* fl = (float4*)f;
#pragma unroll
    for (int i = 0; i < 2; ++i) fl[tid + i * 256] = fg[tid + i * 256];
    __syncthreads();

    const int c = tid & 63;
    const int rg = tid >> 6;  // wave index -> rows rg*4 .. rg*4+3
    float acc0 = 0.f, acc1 = 0.f, acc2 = 0.f, acc3 = 0.f;
    const float4* fv = (const float4*)f;
#pragma unroll
    for (int k = 0; k < IN_FEAT; k += 4) {
        const float wa = w[(k + 0) * OUT_FEAT + c];
        const float wb = w[(k + 1) * OUT_FEAT + c];
        const float wc = w[(k + 2) * OUT_FEAT + c];
        const float wd = w[(k + 3) * OUT_FEAT + c];
        float4 a = fv[((rg * 4 + 0) * IN_FEAT + k) >> 2];
        acc0 += a.x * wa + a.y * wb + a.z * wc + a.w * wd;
        float4 b = fv[((rg * 4 + 1) * IN_FEAT + k) >> 2];
        acc1 += b.x * wa + b.y * wb + b.z * wc + b.w * wd;
        float4 d = fv[((rg * 4 + 2) * IN_FEAT + k) >> 2];
        acc2 += d.x * wa + d.y * wb + d.z * wc + d.w * wd;
        float4 e = fv[((rg * 4 + 3) * IN_FEAT + k) >> 2];
        acc3 += e.x * wa + e.y * wb + e.z * wc + e.w * wd;
    }
    h1[(size_t)(row0 + rg * 4 + 0) * OUT_FEAT + c] = acc0;
    h1[(size_t)(row0 + rg * 4 + 1) * OUT_FEAT + c] = acc1;
    h1[(size_t)(row0 + rg * 4 + 2) * OUT_FEAT + c] = acc2;
    h1[(size_t)(row0 + rg * 4 + 3) * OUT_FEAT + c] = acc3;
}

// ---------------------------------------------------------------------------
// GEMM2: agg1[N,64] @ w2[64,64] (input already rrelu'd by agg kernel)
// ---------------------------------------------------------------------------
__global__ __launch_bounds__(256) void gemm2_kernel(const float* __restrict__ agg1,
                                                    const float* __restrict__ w2,
                                                    float* __restrict__ h2) {
    __shared__ float w[OUT_FEAT * OUT_FEAT];  // 16 KB
    __shared__ float f[16 * OUT_FEAT];        // 4 KB
    const int tid = threadIdx.x;

    const float4* w4 = (const float4*)w2;
    float4* wl = (float4*)w;
#pragma unroll
    for (int i = 0; i < 4; ++i) wl[tid + i * 256] = w4[tid + i * 256];

    const int row0 = blockIdx.x * 16;
    const float4* fg = (const float4*)(agg1 + (size_t)row0 * OUT_FEAT);
    ((float4*)f)[tid] = fg[tid];
    __syncthreads();

    const int c = tid & 63;
    const int rg = tid >> 6;
    float acc0 = 0.f, acc1 = 0.f, acc2 = 0.f, acc3 = 0.f;
    const float4* fv = (const float4*)f;
#pragma unroll
    for (int k = 0; k < OUT_FEAT; k += 4) {
        const float wa = w[(k + 0) * OUT_FEAT + c];
        const float wb = w[(k + 1) * OUT_FEAT + c];
        const float wc = w[(k + 2) * OUT_FEAT + c];
        const float wd = w[(k + 3) * OUT_FEAT + c];
        float4 a = fv[((rg * 4 + 0) * OUT_FEAT + k) >> 2];
        acc0 += a.x * wa + a.y * wb + a.z * wc + a.w * wd;
        float4 b = fv[((rg * 4 + 1) * OUT_FEAT + k) >> 2];
        acc1 += b.x * wa + b.y * wb + b.z * wc + b.w * wd;
        float4 d = fv[((rg * 4 + 2) * OUT_FEAT + k) >> 2];
        acc2 += d.x * wa + d.y * wb + d.z * wc + d.w * wd;
        float4 e = fv[((rg * 4 + 3) * OUT_FEAT + k) >> 2];
        acc3 += e.x * wa + e.y * wb + e.z * wc + e.w * wd;
    }
    h2[(size_t)(row0 + rg * 4 + 0) * OUT_FEAT + c] = acc0;
    h2[(size_t)(row0 + rg * 4 + 1) * OUT_FEAT + c] = acc1;
    h2[(size_t)(row0 + rg * 4 + 2) * OUT_FEAT + c] = acc2;
    h2[(size_t)(row0 + rg * 4 + 3) * OUT_FEAT + c] = acc3;
}

extern "C" void kernel_launch(void* const* d_in, const int* in_sizes, int n_in,
                              void* d_out, int out_size, void* d_ws, size_t ws_size,
                              hipStream_t stream) {
    const float* feat = (const float*)d_in[0];
    const int*   src  = (const int*)d_in[1];
    const int*   dst  = (const int*)d_in[2];
    const float* w1   = (const float*)d_in[3];
    const float* w2   = (const float*)d_in[4];
    float* out = (float*)d_out;

    // workspace layout
    float* h       = (float*)d_ws;                    // 100000*64 f32 = 25.6 MB
    int*   csr     = (int*)(h + (size_t)N_NODES * OUT_FEAT);  // 1.6M ints
    int*   cnt     = csr + N_EDGES;                   // 100k
    int*   counter = cnt + N_NODES;                   // 1
    int*   ptr     = counter + 1;                     // 100k
    int*   cur     = ptr + N_NODES;                   // 100k

    // ---- build CSR by dst (once; reused for both layers) ----
    hipMemsetAsync(cnt, 0, (size_t)(N_NODES + 1) * sizeof(int), stream);  // cnt+counter
    hist_kernel<<<N_EDGES / 256, 256, 0, stream>>>(dst, cnt);
    offsets_kernel<<<(N_NODES + 255) / 256, 256, 0, stream>>>(cnt, ptr, cur, counter);
    fill_kernel<<<N_EDGES / 256, 256, 0, stream>>>(src, dst, cur, csr);

    // ---- layer 1 ----
    gemm1_kernel<<<N_NODES / 16, 256, 0, stream>>>(feat, w1, h);
    agg_rrelu_kernel<<<(N_NODES + 3) / 4, 256, 0, stream>>>(h, csr, ptr, cnt, out);

    // ---- layer 2 ----
    gemm2_kernel<<<N_NODES / 16, 256, 0, stream>>>(out, w2, h);
    agg_rrelu_kernel<<<(N_NODES + 3) / 4, 256, 0, stream>>>(h, csr, ptr, cnt, out);
}